// Round 1
// baseline (61.802 us; speedup 1.0000x reference)
//
#include <hip/hip_runtime.h>
#include <hip/hip_bf16.h>

// Problem constants
#define M_TOT 16384   // B*T*H*W = 2*8*32*32
#define D_    256
#define K_DIM 256

typedef __attribute__((ext_vector_type(4))) float f32x4;
typedef __attribute__((ext_vector_type(8))) short s16x8;
typedef __attribute__((ext_vector_type(4))) short s16x4;

typedef const __attribute__((address_space(1))) void* gptr_t;
typedef __attribute__((address_space(3))) void* lptr_t;

__device__ __forceinline__ unsigned short f2bf(float f) {
  unsigned x = __float_as_uint(f);
  return (unsigned short)((x + 0x7fffu + ((x >> 16) & 1u)) >> 16);
}
__device__ __forceinline__ float bf2f(short s) {
  return __uint_as_float(((unsigned)(unsigned short)s) << 16);
}

// ---------------- LayerNorm: one wave per token (D=256 = 64 lanes * f32x4) ----
__global__ __launch_bounds__(256) void ln_kernel(const float* __restrict__ x,
                                                 const float* __restrict__ g,
                                                 const float* __restrict__ b,
                                                 unsigned short* __restrict__ xn) {
  int tok  = blockIdx.x * 4 + (threadIdx.x >> 6);
  int lane = threadIdx.x & 63;
  f32x4 v = ((const f32x4*)(x + (size_t)tok * D_))[lane];
  float s = 0.f, s2 = 0.f;
#pragma unroll
  for (int i = 0; i < 4; ++i) { s += v[i]; s2 += v[i] * v[i]; }
#pragma unroll
  for (int o = 1; o < 64; o <<= 1) { s += __shfl_xor(s, o); s2 += __shfl_xor(s2, o); }
  float mu   = s * (1.0f / 256.0f);
  float rstd = rsqrtf(s2 * (1.0f / 256.0f) - mu * mu + 1e-5f);
  f32x4 gv = ((const f32x4*)g)[lane];
  f32x4 bv = ((const f32x4*)b)[lane];
  s16x4 o4;
#pragma unroll
  for (int i = 0; i < 4; ++i) o4[i] = (short)f2bf((v[i] - mu) * rstd * gv[i] + bv[i]);
  ((s16x4*)(xn + (size_t)tok * D_))[lane] = o4;
}

// ------------- Weight transpose + fp32->bf16: Wt[outcol][k] ------------------
__global__ void wtrans_kernel(const float* __restrict__ wq, const float* __restrict__ wk,
                              const float* __restrict__ wv, const float* __restrict__ wo,
                              unsigned short* __restrict__ wt_qkv,
                              unsigned short* __restrict__ wt_o) {
  __shared__ float tile[32][33];
  int z = blockIdx.z;  // 0=wq 1=wk 2=wv 3=wo
  const float* src = (z == 0) ? wq : (z == 1) ? wk : (z == 2) ? wv : wo;
  int k0 = blockIdx.x * 32, n0 = blockIdx.y * 32;
  int tx = threadIdx.x, ty = threadIdx.y;  // block (32,8)
#pragma unroll
  for (int i = 0; i < 4; ++i) {
    int r = ty + i * 8;
    tile[r][tx] = src[(size_t)(k0 + r) * D_ + n0 + tx];
  }
  __syncthreads();
  unsigned short* dst = (z < 3) ? (wt_qkv + (size_t)(z * 256 + n0) * K_DIM + k0)
                                : (wt_o + (size_t)n0 * K_DIM + k0);
#pragma unroll
  for (int i = 0; i < 4; ++i) {
    int r = ty + i * 8;
    dst[(size_t)r * K_DIM + tx] = f2bf(tile[tx][r]);
  }
}

// ------------------ GEMM: C[M][N] = A[M][256] * Bt[N][256]^T -----------------
// 128x128 tile, BK=64, 4 waves (2x2), each wave 64x64 via 4x4 mfma 16x16x32.
// LDS: linear dest for global_load_lds, XOR-swizzled source + swizzled ds_read.
// EPI 0: bf16 out with per-256-block bias (b0/b1/b2).  EPI 1: fp32 out + b0 + resid.
template <int EPI>
__global__ __launch_bounds__(256) void gemm_kernel(
    const unsigned short* __restrict__ A, const unsigned short* __restrict__ Bt,
    const float* __restrict__ b0, const float* __restrict__ b1, const float* __restrict__ b2,
    const float* __restrict__ resid, void* __restrict__ Cv, int ldc) {
  __shared__ __align__(16) char smem[32768];
  char* Asm = smem;            // [128][64] bf16 (128B rows), swizzled
  char* Bsm = smem + 16384;
  const int tid  = threadIdx.x;
  const int wid  = tid >> 6;
  const int lane = tid & 63;
  const int m0 = blockIdx.y * 128;
  const int n0 = blockIdx.x * 128;
  const int wave_m = wid >> 1;
  const int wave_n = wid & 1;

  f32x4 acc[4][4] = {};

  for (int ks = 0; ks < 4; ++ks) {
    const int kk0 = ks * 64;
    __syncthreads();  // previous compute done before LDS overwrite
#pragma unroll
    for (int it = 0; it < 4; ++it) {
      int base     = (it * 256 + wid * 64) * 16;  // wave-uniform LDS byte base
      int lane_lin = base + lane * 16;
      int row  = lane_lin >> 7;                   // 128B per row
      int off  = lane_lin & 127;
      int soff = off ^ ((row & 7) << 4);          // inverse swizzle on SOURCE
      const char* ga = (const char*)(A + (size_t)(m0 + row) * K_DIM + kk0) + soff;
      const char* gb = (const char*)(Bt + (size_t)(n0 + row) * K_DIM + kk0) + soff;
      __builtin_amdgcn_global_load_lds((gptr_t)ga, (lptr_t)(Asm + base), 16, 0, 0);
      __builtin_amdgcn_global_load_lds((gptr_t)gb, (lptr_t)(Bsm + base), 16, 0, 0);
    }
    __syncthreads();  // compiler drains vmcnt before barrier

#pragma unroll
    for (int kk = 0; kk < 2; ++kk) {
      s16x8 af[4], bf[4];
#pragma unroll
      for (int m = 0; m < 4; ++m) {
        int r    = wave_m * 64 + m * 16 + (lane & 15);
        int byte = kk * 64 + ((lane >> 4) * 16);
        af[m] = *(const s16x8*)(Asm + r * 128 + (byte ^ ((r & 7) << 4)));
      }
#pragma unroll
      for (int n = 0; n < 4; ++n) {
        int r    = wave_n * 64 + n * 16 + (lane & 15);
        int byte = kk * 64 + ((lane >> 4) * 16);
        bf[n] = *(const s16x8*)(Bsm + r * 128 + (byte ^ ((r & 7) << 4)));
      }
#pragma unroll
      for (int m = 0; m < 4; ++m)
#pragma unroll
        for (int n = 0; n < 4; ++n)
          acc[m][n] = __builtin_amdgcn_mfma_f32_16x16x32_bf16(af[m], bf[n], acc[m][n], 0, 0, 0);
    }
  }

  // Epilogue. C/D layout: col = lane&15, row = (lane>>4)*4 + reg  [m89-verified]
  const int c0 = lane & 15;
  const int r0 = (lane >> 4) * 4;
#pragma unroll
  for (int m = 0; m < 4; ++m) {
#pragma unroll
    for (int n = 0; n < 4; ++n) {
      int row = m0 + wave_m * 64 + m * 16 + r0;
      int col = n0 + wave_n * 64 + n * 16 + c0;
#pragma unroll
      for (int r = 0; r < 4; ++r) {
        float val = acc[m][n][r];
        if (EPI == 0) {
          const float* bias = (col < 256) ? b0 : (col < 512) ? b1 : b2;
          val += bias[col & 255];
          ((unsigned short*)Cv)[(size_t)(row + r) * ldc + col] = f2bf(val);
        } else {
          val += b0[col] + resid[(size_t)(row + r) * D_ + col];
          ((float*)Cv)[(size_t)(row + r) * ldc + col] = val;
        }
      }
    }
  }
}

// ---------------- Local attention: one wave per token, 8 heads ---------------
// lane -> head = lane/8, d = (lane%8)*4 within head? No: d = lane*4 globally,
// head = (lane*4)/32 = lane/8; 8-lane groups reduce via shfl_xor(1,2,4).
__global__ __launch_bounds__(256) void attn_kernel(const unsigned short* __restrict__ qkv,
                                                   unsigned short* __restrict__ aout) {
  int tok  = blockIdx.x * 4 + (threadIdx.x >> 6);
  int lane = threadIdx.x & 63;
  int bt = tok >> 10;
  int n  = tok & 1023;
  int h  = n >> 5, w = n & 31;
  const size_t rowq = (size_t)tok * 768;
  s16x4 qr = *(const s16x4*)(qkv + rowq + lane * 4);
  f32x4 q;
#pragma unroll
  for (int i = 0; i < 4; ++i) q[i] = bf2f(qr[i]);

  f32x4 vst[9];
  float sc[9];
#pragma unroll
  for (int dh = -1; dh <= 1; ++dh) {
#pragma unroll
    for (int dw = -1; dw <= 1; ++dw) {
      const int j = (dh + 1) * 3 + (dw + 1);
      int nh = min(max(h + dh, 0), 31);
      int nw = min(max(w + dw, 0), 31);
      size_t nrow = (size_t)((bt << 10) + (nh << 5) + nw) * 768;
      s16x4 kr = *(const s16x4*)(qkv + nrow + 256 + lane * 4);
      s16x4 vr = *(const s16x4*)(qkv + nrow + 512 + lane * 4);
      float p = 0.f;
      f32x4 vv;
#pragma unroll
      for (int i = 0; i < 4; ++i) { p += q[i] * bf2f(kr[i]); vv[i] = bf2f(vr[i]); }
      p += __shfl_xor(p, 1);
      p += __shfl_xor(p, 2);
      p += __shfl_xor(p, 4);
      sc[j]  = p * 0.17677669529663687f;  // 1/sqrt(32)
      vst[j] = vv;
    }
  }
  float mx = sc[0];
#pragma unroll
  for (int j = 1; j < 9; ++j) mx = fmaxf(mx, sc[j]);
  float den = 0.f;
#pragma unroll
  for (int j = 0; j < 9; ++j) { sc[j] = __expf(sc[j] - mx); den += sc[j]; }
  float inv = 1.0f / den;
  f32x4 o = {};
#pragma unroll
  for (int j = 0; j < 9; ++j) {
    float wgt = sc[j] * inv;
#pragma unroll
    for (int i = 0; i < 4; ++i) o[i] += wgt * vst[j][i];
  }
  s16x4 ov;
#pragma unroll
  for (int i = 0; i < 4; ++i) ov[i] = (short)f2bf(o[i]);
  *(s16x4*)(aout + (size_t)tok * 256 + lane * 4) = ov;
}

extern "C" void kernel_launch(void* const* d_in, const int* in_sizes, int n_in,
                              void* d_out, int out_size, void* d_ws, size_t ws_size,
                              hipStream_t stream) {
  const float* x  = (const float*)d_in[0];
  const float* lg = (const float*)d_in[1];
  const float* lb = (const float*)d_in[2];
  const float* wq = (const float*)d_in[3];
  const float* bq = (const float*)d_in[4];
  const float* wk = (const float*)d_in[5];
  const float* bk = (const float*)d_in[6];
  const float* wv = (const float*)d_in[7];
  const float* bv = (const float*)d_in[8];
  const float* wo = (const float*)d_in[9];
  const float* bo = (const float*)d_in[10];
  float* out = (float*)d_out;

  // workspace layout (bytes): xn/aout share (xn dead after QKV GEMM)
  char* ws = (char*)d_ws;
  unsigned short* xn    = (unsigned short*)ws;                 // 16384*256*2 = 8388608
  unsigned short* aoutb = (unsigned short*)ws;                 // reuse xn region
  unsigned short* qkv   = (unsigned short*)(ws + 8388608);     // 16384*768*2 = 25165824
  unsigned short* wtqkv = (unsigned short*)(ws + 33554432);    // 768*256*2   = 393216
  unsigned short* wto   = (unsigned short*)(ws + 33947648);    // 256*256*2   = 131072
  // total 34,078,720 bytes

  ln_kernel<<<4096, 256, 0, stream>>>(x, lg, lb, xn);
  wtrans_kernel<<<dim3(8, 8, 4), dim3(32, 8), 0, stream>>>(wq, wk, wv, wo, wtqkv, wto);
  gemm_kernel<0><<<dim3(6, 128), 256, 0, stream>>>(xn, wtqkv, bq, bk, bv, nullptr,
                                                   (void*)qkv, 768);
  attn_kernel<<<4096, 256, 0, stream>>>(qkv, aoutb);
  gemm_kernel<1><<<dim3(2, 128), 256, 0, stream>>>(aoutb, wto, bo, nullptr, nullptr, x,
                                                   (void*)out, 256);
}

// Round 2
// 44.417 us; speedup vs baseline: 1.3914x; 1.3914x over previous
//
#include <hip/hip_runtime.h>
#include <hip/hip_bf16.h>

#define M_TOT 16384   // B*T*H*W = 2*8*32*32
#define D_    256
#define K_DIM 256

typedef __attribute__((ext_vector_type(4))) float f32x4;
typedef __attribute__((ext_vector_type(8))) short s16x8;
typedef __attribute__((ext_vector_type(4))) short s16x4;

typedef const __attribute__((address_space(1))) void* gptr_t;
typedef __attribute__((address_space(3))) void* lptr_t;

__device__ __forceinline__ unsigned short f2bf(float f) {
  unsigned x = __float_as_uint(f);
  return (unsigned short)((x + 0x7fffu + ((x >> 16) & 1u)) >> 16);
}
__device__ __forceinline__ float bf2f(short s) {
  return __uint_as_float(((unsigned)(unsigned short)s) << 16);
}

// ---------- prep: blocks [0,4096) = LayerNorm, [4096,4352) = weight transpose ----------
__global__ __launch_bounds__(256) void prep_kernel(
    const float* __restrict__ x, const float* __restrict__ g, const float* __restrict__ b,
    unsigned short* __restrict__ xn,
    const float* __restrict__ wq, const float* __restrict__ wk,
    const float* __restrict__ wv, const float* __restrict__ wo,
    unsigned short* __restrict__ wt_qkv, unsigned short* __restrict__ wt_o) {
  __shared__ float tile[32][33];
  int tid = threadIdx.x;
  if (blockIdx.x < 4096) {
    // LayerNorm: one wave per token (D=256 = 64 lanes * f32x4)
    int tok  = blockIdx.x * 4 + (tid >> 6);
    int lane = tid & 63;
    f32x4 v = ((const f32x4*)(x + (size_t)tok * D_))[lane];
    float s = 0.f, s2 = 0.f;
#pragma unroll
    for (int i = 0; i < 4; ++i) { s += v[i]; s2 += v[i] * v[i]; }
#pragma unroll
    for (int o = 1; o < 64; o <<= 1) { s += __shfl_xor(s, o); s2 += __shfl_xor(s2, o); }
    float mu   = s * (1.0f / 256.0f);
    float rstd = rsqrtf(s2 * (1.0f / 256.0f) - mu * mu + 1e-5f);
    f32x4 gv = ((const f32x4*)g)[lane];
    f32x4 bv = ((const f32x4*)b)[lane];
    s16x4 o4;
#pragma unroll
    for (int i = 0; i < 4; ++i) o4[i] = (short)f2bf((v[i] - mu) * rstd * gv[i] + bv[i]);
    ((s16x4*)(xn + (size_t)tok * D_))[lane] = o4;
  } else {
    // weight transpose + cast: Wt[outcol][k]
    int bid = blockIdx.x - 4096;     // 0..255
    int z   = bid >> 6;              // 0=wq 1=wk 2=wv 3=wo
    int rem = bid & 63;
    int k0 = (rem & 7) * 32, n0 = (rem >> 3) * 32;
    int tx = tid & 31, ty = tid >> 5;  // (32,8)
    const float* src = (z == 0) ? wq : (z == 1) ? wk : (z == 2) ? wv : wo;
#pragma unroll
    for (int i = 0; i < 4; ++i) {
      int r = ty + i * 8;
      tile[r][tx] = src[(size_t)(k0 + r) * D_ + n0 + tx];
    }
    __syncthreads();
    unsigned short* dst = (z < 3) ? (wt_qkv + (size_t)(z * 256 + n0) * K_DIM + k0)
                                  : (wt_o + (size_t)n0 * K_DIM + k0);
#pragma unroll
    for (int i = 0; i < 4; ++i) {
      int r = ty + i * 8;
      dst[(size_t)r * K_DIM + tx] = f2bf(tile[tx][r]);
    }
  }
}

// ---------------- QKV GEMM: C[M][768] = A[M][256] * Bt[768][256]^T -----------
// 128x128 tile, BK=64, 4 waves (2x2), each wave 64x64 via 4x4 mfma 16x16x32.
// XCD-aware block swizzle (768 % 8 == 0, bijective).
__global__ __launch_bounds__(256) void gemm_qkv_kernel(
    const unsigned short* __restrict__ A, const unsigned short* __restrict__ Bt,
    const float* __restrict__ b0, const float* __restrict__ b1, const float* __restrict__ b2,
    unsigned short* __restrict__ C) {
  __shared__ __align__(16) char smem[32768];
  char* Asm = smem;            // [128][64] bf16 (128B rows), swizzled
  char* Bsm = smem + 16384;
  const int tid  = threadIdx.x;
  const int wid  = tid >> 6;
  const int lane = tid & 63;
  // XCD swizzle: 768 blocks, 8 XCDs, 96 per chunk
  int lin = blockIdx.y * 6 + blockIdx.x;
  int swz = (lin & 7) * 96 + (lin >> 3);
  const int m0 = (swz / 6) * 128;
  const int n0 = (swz % 6) * 128;
  const int wave_m = wid >> 1;
  const int wave_n = wid & 1;

  f32x4 acc[4][4] = {};

  for (int ks = 0; ks < 4; ++ks) {
    const int kk0 = ks * 64;
    __syncthreads();
#pragma unroll
    for (int it = 0; it < 4; ++it) {
      int base     = (it * 256 + wid * 64) * 16;
      int lane_lin = base + lane * 16;
      int row  = lane_lin >> 7;
      int off  = lane_lin & 127;
      int soff = off ^ ((row & 7) << 4);
      const char* ga = (const char*)(A + (size_t)(m0 + row) * K_DIM + kk0) + soff;
      const char* gb = (const char*)(Bt + (size_t)(n0 + row) * K_DIM + kk0) + soff;
      __builtin_amdgcn_global_load_lds((gptr_t)ga, (lptr_t)(Asm + base), 16, 0, 0);
      __builtin_amdgcn_global_load_lds((gptr_t)gb, (lptr_t)(Bsm + base), 16, 0, 0);
    }
    __syncthreads();

#pragma unroll
    for (int kk = 0; kk < 2; ++kk) {
      s16x8 af[4], bf[4];
#pragma unroll
      for (int m = 0; m < 4; ++m) {
        int r    = wave_m * 64 + m * 16 + (lane & 15);
        int byte = kk * 64 + ((lane >> 4) * 16);
        af[m] = *(const s16x8*)(Asm + r * 128 + (byte ^ ((r & 7) << 4)));
      }
#pragma unroll
      for (int n = 0; n < 4; ++n) {
        int r    = wave_n * 64 + n * 16 + (lane & 15);
        int byte = kk * 64 + ((lane >> 4) * 16);
        bf[n] = *(const s16x8*)(Bsm + r * 128 + (byte ^ ((r & 7) << 4)));
      }
#pragma unroll
      for (int m = 0; m < 4; ++m)
#pragma unroll
        for (int n = 0; n < 4; ++n)
          acc[m][n] = __builtin_amdgcn_mfma_f32_16x16x32_bf16(af[m], bf[n], acc[m][n], 0, 0, 0);
    }
  }

  // C/D layout: col = lane&15, row = (lane>>4)*4 + reg
  const int c0 = lane & 15;
  const int r0 = (lane >> 4) * 4;
#pragma unroll
  for (int m = 0; m < 4; ++m) {
#pragma unroll
    for (int n = 0; n < 4; ++n) {
      int row = m0 + wave_m * 64 + m * 16 + r0;
      int col = n0 + wave_n * 64 + n * 16 + c0;
      const float* bias = (col < 256) ? b0 : (col < 512) ? b1 : b2;
      float bb = bias[col & 255];
#pragma unroll
      for (int r = 0; r < 4; ++r)
        C[(size_t)(row + r) * 768 + col] = f2bf(acc[m][n][r] + bb);
    }
  }
}

// -------- Fused local-attention + output GEMM + bias + residual --------------
// Grid: 256 blocks x 512 threads (8 waves). Block handles 64 tokens.
// Phase 1: attention for 64 tokens -> bf16 A-tile in LDS (swizzled [64][512B]).
// Phase 2: C[64][256] = A @ Wo^T, staged B per K-step, + bo + x residual.
__global__ __launch_bounds__(512) void attn_ogemm_kernel(
    const unsigned short* __restrict__ qkv, const unsigned short* __restrict__ wto,
    const float* __restrict__ bo, const float* __restrict__ x,
    float* __restrict__ out) {
  __shared__ __align__(16) char smem[65536];
  char* Asm = smem;          // [64][256 bf16 = 512B], XOR-swizzled within 128B
  char* Bsm = smem + 32768;  // [256][64 bf16 = 128B] per K-step, swizzled
  const int tid  = threadIdx.x;
  const int wid  = tid >> 6;
  const int lane = tid & 63;
  const int m0 = blockIdx.x * 64;

  // ---- Phase 1: attention, 8 tokens per wave ----
#pragma unroll
  for (int t8 = 0; t8 < 8; ++t8) {
    int t   = wid * 8 + t8;
    int tok = m0 + t;
    int bt = tok >> 10;
    int n  = tok & 1023;
    int h  = n >> 5, w = n & 31;
    const size_t rowq = (size_t)tok * 768;
    s16x4 qr = *(const s16x4*)(qkv + rowq + lane * 4);
    f32x4 q;
#pragma unroll
    for (int i = 0; i < 4; ++i) q[i] = bf2f(qr[i]);

    f32x4 vst[9];
    float sc[9];
#pragma unroll
    for (int dh = -1; dh <= 1; ++dh) {
#pragma unroll
      for (int dw = -1; dw <= 1; ++dw) {
        const int j = (dh + 1) * 3 + (dw + 1);
        int nh = min(max(h + dh, 0), 31);
        int nw = min(max(w + dw, 0), 31);
        size_t nrow = (size_t)((bt << 10) + (nh << 5) + nw) * 768;
        s16x4 kr = *(const s16x4*)(qkv + nrow + 256 + lane * 4);
        s16x4 vr = *(const s16x4*)(qkv + nrow + 512 + lane * 4);
        float p = 0.f;
        f32x4 vv;
#pragma unroll
        for (int i = 0; i < 4; ++i) { p += q[i] * bf2f(kr[i]); vv[i] = bf2f(vr[i]); }
        p += __shfl_xor(p, 1);
        p += __shfl_xor(p, 2);
        p += __shfl_xor(p, 4);
        sc[j]  = p * 0.17677669529663687f;  // 1/sqrt(32)
        vst[j] = vv;
      }
    }
    float mx = sc[0];
#pragma unroll
    for (int j = 1; j < 9; ++j) mx = fmaxf(mx, sc[j]);
    float den = 0.f;
#pragma unroll
    for (int j = 0; j < 9; ++j) { sc[j] = __expf(sc[j] - mx); den += sc[j]; }
    float inv = 1.0f / den;
    f32x4 o = {};
#pragma unroll
    for (int j = 0; j < 9; ++j) {
      float wgt = sc[j] * inv;
#pragma unroll
      for (int i = 0; i < 4; ++i) o[i] += wgt * vst[j][i];
    }
    s16x4 ov;
#pragma unroll
    for (int i = 0; i < 4; ++i) ov[i] = (short)f2bf(o[i]);
    // write to A-LDS, row t, logical byte lane*8, swizzled within 128B window
    int byte = (lane * 8) ^ ((t & 7) << 4);
    *(s16x4*)(Asm + t * 512 + byte) = ov;
  }

  // ---- Phase 2: GEMM. wave (wid>>2) = m-half (32 rows), (wid&3) = n-quarter (64 cols)
  const int wave_m = wid >> 2;
  const int wave_n = wid & 3;
  f32x4 acc[2][4] = {};

  for (int ks = 0; ks < 4; ++ks) {
    __syncthreads();  // Asm ready (ks=0) / prev ks done reading Bsm
#pragma unroll
    for (int it = 0; it < 4; ++it) {
      int base     = (it * 512 + wid * 64) * 16;
      int lane_lin = base + lane * 16;
      int row  = lane_lin >> 7;   // 128B rows
      int off  = lane_lin & 127;
      int soff = off ^ ((row & 7) << 4);
      const char* gb = (const char*)(wto + (size_t)row * K_DIM + ks * 64) + soff;
      __builtin_amdgcn_global_load_lds((gptr_t)gb, (lptr_t)(Bsm + base), 16, 0, 0);
    }
    __syncthreads();

#pragma unroll
    for (int kk = 0; kk < 2; ++kk) {
      s16x8 af[2], bf[4];
#pragma unroll
      for (int m = 0; m < 2; ++m) {
        int r    = wave_m * 32 + m * 16 + (lane & 15);
        int byte = ks * 128 + kk * 64 + ((lane >> 4) * 16);
        af[m] = *(const s16x8*)(Asm + r * 512 + (byte ^ ((r & 7) << 4)));
      }
#pragma unroll
      for (int n = 0; n < 4; ++n) {
        int r    = wave_n * 64 + n * 16 + (lane & 15);
        int byte = kk * 64 + ((lane >> 4) * 16);
        bf[n] = *(const s16x8*)(Bsm + r * 128 + (byte ^ ((r & 7) << 4)));
      }
#pragma unroll
      for (int m = 0; m < 2; ++m)
#pragma unroll
        for (int n = 0; n < 4; ++n)
          acc[m][n] = __builtin_amdgcn_mfma_f32_16x16x32_bf16(af[m], bf[n], acc[m][n], 0, 0, 0);
    }
  }

  // epilogue: + bo + residual, fp32 out
  const int c0 = lane & 15;
  const int r0 = (lane >> 4) * 4;
#pragma unroll
  for (int m = 0; m < 2; ++m) {
#pragma unroll
    for (int n = 0; n < 4; ++n) {
      int row = m0 + wave_m * 32 + m * 16 + r0;
      int col = wave_n * 64 + n * 16 + c0;
      float bb = bo[col];
#pragma unroll
      for (int r = 0; r < 4; ++r)
        out[(size_t)(row + r) * D_ + col] =
            acc[m][n][r] + bb + x[(size_t)(row + r) * D_ + col];
    }
  }
}

extern "C" void kernel_launch(void* const* d_in, const int* in_sizes, int n_in,
                              void* d_out, int out_size, void* d_ws, size_t ws_size,
                              hipStream_t stream) {
  const float* x  = (const float*)d_in[0];
  const float* lg = (const float*)d_in[1];
  const float* lb = (const float*)d_in[2];
  const float* wq = (const float*)d_in[3];
  const float* bq = (const float*)d_in[4];
  const float* wk = (const float*)d_in[5];
  const float* bk = (const float*)d_in[6];
  const float* wv = (const float*)d_in[7];
  const float* bv = (const float*)d_in[8];
  const float* wo = (const float*)d_in[9];
  const float* bo = (const float*)d_in[10];
  float* out = (float*)d_out;

  char* ws = (char*)d_ws;
  unsigned short* xn    = (unsigned short*)ws;                 // 16384*256*2 = 8388608
  unsigned short* qkv   = (unsigned short*)(ws + 8388608);     // 16384*768*2 = 25165824
  unsigned short* wtqkv = (unsigned short*)(ws + 33554432);    // 768*256*2   = 393216
  unsigned short* wto   = (unsigned short*)(ws + 33947648);    // 256*256*2   = 131072

  prep_kernel<<<4352, 256, 0, stream>>>(x, lg, lb, xn, wq, wk, wv, wo, wtqkv, wto);
  gemm_qkv_kernel<<<dim3(6, 128), 256, 0, stream>>>(xn, wtqkv, bq, bk, bv, qkv);
  attn_ogemm_kernel<<<256, 512, 0, stream>>>(qkv, wto, bo, x, out);
}

// Round 3
// 41.399 us; speedup vs baseline: 1.4928x; 1.0729x over previous
//
#include <hip/hip_runtime.h>
#include <hip/hip_bf16.h>

#define M_TOT 16384   // B*T*H*W = 2*8*32*32
#define D_    256
#define K_DIM 256

typedef __attribute__((ext_vector_type(4))) float f32x4;
typedef __attribute__((ext_vector_type(8))) short s16x8;
typedef __attribute__((ext_vector_type(4))) short s16x4;

typedef const __attribute__((address_space(1))) void* gptr_t;
typedef __attribute__((address_space(3))) void* lptr_t;

__device__ __forceinline__ unsigned short f2bf(float f) {
  unsigned x = __float_as_uint(f);
  return (unsigned short)((x + 0x7fffu + ((x >> 16) & 1u)) >> 16);
}
__device__ __forceinline__ float bf2f(short s) {
  return __uint_as_float(((unsigned)(unsigned short)s) << 16);
}

// ---------- prep: blocks [0,4096) = LayerNorm, [4096,4352) = weight transpose ----------
__global__ __launch_bounds__(256) void prep_kernel(
    const float* __restrict__ x, const float* __restrict__ g, const float* __restrict__ b,
    unsigned short* __restrict__ xn,
    const float* __restrict__ wq, const float* __restrict__ wk,
    const float* __restrict__ wv, const float* __restrict__ wo,
    unsigned short* __restrict__ wt_qkv, unsigned short* __restrict__ wt_o) {
  __shared__ float tile[32][33];
  int tid = threadIdx.x;
  if (blockIdx.x < 4096) {
    int tok  = blockIdx.x * 4 + (tid >> 6);
    int lane = tid & 63;
    f32x4 v = ((const f32x4*)(x + (size_t)tok * D_))[lane];
    float s = 0.f, s2 = 0.f;
#pragma unroll
    for (int i = 0; i < 4; ++i) { s += v[i]; s2 += v[i] * v[i]; }
#pragma unroll
    for (int o = 1; o < 64; o <<= 1) { s += __shfl_xor(s, o); s2 += __shfl_xor(s2, o); }
    float mu   = s * (1.0f / 256.0f);
    float rstd = rsqrtf(s2 * (1.0f / 256.0f) - mu * mu + 1e-5f);
    f32x4 gv = ((const f32x4*)g)[lane];
    f32x4 bv = ((const f32x4*)b)[lane];
    s16x4 o4;
#pragma unroll
    for (int i = 0; i < 4; ++i) o4[i] = (short)f2bf((v[i] - mu) * rstd * gv[i] + bv[i]);
    ((s16x4*)(xn + (size_t)tok * D_))[lane] = o4;
  } else {
    int bid = blockIdx.x - 4096;     // 0..255
    int z   = bid >> 6;              // 0=wq 1=wk 2=wv 3=wo
    int rem = bid & 63;
    int k0 = (rem & 7) * 32, n0 = (rem >> 3) * 32;
    int tx = tid & 31, ty = tid >> 5;  // (32,8)
    const float* src = (z == 0) ? wq : (z == 1) ? wk : (z == 2) ? wv : wo;
#pragma unroll
    for (int i = 0; i < 4; ++i) {
      int r = ty + i * 8;
      tile[r][tx] = src[(size_t)(k0 + r) * D_ + n0 + tx];
    }
    __syncthreads();
    unsigned short* dst = (z < 3) ? (wt_qkv + (size_t)(z * 256 + n0) * K_DIM + k0)
                                  : (wt_o + (size_t)n0 * K_DIM + k0);
#pragma unroll
    for (int i = 0; i < 4; ++i) {
      int r = ty + i * 8;
      dst[(size_t)r * K_DIM + tx] = f2bf(tile[tx][r]);
    }
  }
}

// ---------------- QKV GEMM: C[M][768] = A[M][256] * Bt[768][256]^T -----------
__global__ __launch_bounds__(256) void gemm_qkv_kernel(
    const unsigned short* __restrict__ A, const unsigned short* __restrict__ Bt,
    const float* __restrict__ b0, const float* __restrict__ b1, const float* __restrict__ b2,
    unsigned short* __restrict__ C) {
  __shared__ __align__(16) char smem[32768];
  char* Asm = smem;            // [128][64] bf16 (128B rows), swizzled
  char* Bsm = smem + 16384;
  const int tid  = threadIdx.x;
  const int wid  = tid >> 6;
  const int lane = tid & 63;
  int lin = blockIdx.y * 6 + blockIdx.x;
  int swz = (lin & 7) * 96 + (lin >> 3);   // 768 blocks, bijective XCD swizzle
  const int m0 = (swz / 6) * 128;
  const int n0 = (swz % 6) * 128;
  const int wave_m = wid >> 1;
  const int wave_n = wid & 1;

  f32x4 acc[4][4] = {};

  for (int ks = 0; ks < 4; ++ks) {
    const int kk0 = ks * 64;
    __syncthreads();
#pragma unroll
    for (int it = 0; it < 4; ++it) {
      int base     = (it * 256 + wid * 64) * 16;
      int lane_lin = base + lane * 16;
      int row  = lane_lin >> 7;
      int off  = lane_lin & 127;
      int soff = off ^ ((row & 7) << 4);
      const char* ga = (const char*)(A + (size_t)(m0 + row) * K_DIM + kk0) + soff;
      const char* gb = (const char*)(Bt + (size_t)(n0 + row) * K_DIM + kk0) + soff;
      __builtin_amdgcn_global_load_lds((gptr_t)ga, (lptr_t)(Asm + base), 16, 0, 0);
      __builtin_amdgcn_global_load_lds((gptr_t)gb, (lptr_t)(Bsm + base), 16, 0, 0);
    }
    __syncthreads();

#pragma unroll
    for (int kk = 0; kk < 2; ++kk) {
      s16x8 af[4], bf[4];
#pragma unroll
      for (int m = 0; m < 4; ++m) {
        int r    = wave_m * 64 + m * 16 + (lane & 15);
        int byte = kk * 64 + ((lane >> 4) * 16);
        af[m] = *(const s16x8*)(Asm + r * 128 + (byte ^ ((r & 7) << 4)));
      }
#pragma unroll
      for (int n = 0; n < 4; ++n) {
        int r    = wave_n * 64 + n * 16 + (lane & 15);
        int byte = kk * 64 + ((lane >> 4) * 16);
        bf[n] = *(const s16x8*)(Bsm + r * 128 + (byte ^ ((r & 7) << 4)));
      }
#pragma unroll
      for (int m = 0; m < 4; ++m)
#pragma unroll
        for (int n = 0; n < 4; ++n)
          acc[m][n] = __builtin_amdgcn_mfma_f32_16x16x32_bf16(af[m], bf[n], acc[m][n], 0, 0, 0);
    }
  }

  const int c0 = lane & 15;
  const int r0 = (lane >> 4) * 4;
#pragma unroll
  for (int m = 0; m < 4; ++m) {
#pragma unroll
    for (int n = 0; n < 4; ++n) {
      int row = m0 + wave_m * 64 + m * 16 + r0;
      int col = n0 + wave_n * 64 + n * 16 + c0;
      const float* bias = (col < 256) ? b0 : (col < 512) ? b1 : b2;
      float bb = bias[col & 255];
#pragma unroll
      for (int r = 0; r < 4; ++r)
        C[(size_t)(row + r) * 768 + col] = f2bf(acc[m][n][r] + bb);
    }
  }
}

// -------- Fused local-attention + output GEMM + bias + residual --------------
// Block = one image row (32 tokens), 512 threads (8 waves). Grid 512.
// Phase 1a: K-halo (3 image rows x 32 tok x 512B = 48KB) -> LDS, scores+softmax.
// Phase 1b: V-halo overwrites same LDS, weighted sum -> swizzled A-tile (16KB).
// Phase 2:  C[32][256] = A @ Wo^T (+bo +x), Bsm reuses halo LDS.
__global__ __launch_bounds__(512) void attn_ogemm_kernel(
    const unsigned short* __restrict__ qkv, const unsigned short* __restrict__ wto,
    const float* __restrict__ bo, const float* __restrict__ x,
    float* __restrict__ out) {
  __shared__ __align__(16) char smem[65536];
  char* Halo = smem;           // 48KB phase 1 (K then V); Bsm (32KB) in phase 2
  char* Asm  = smem + 49152;   // [32 tok][512B], XOR-swizzled
  const int tid  = threadIdx.x;
  const int wid  = tid >> 6;
  const int lane = tid & 63;
  // XCD-bijective swizzle: 512 blocks -> 64 consecutive image-rows per XCD
  int bswz = (blockIdx.x & 7) * 64 + (blockIdx.x >> 3);
  const int bt = bswz >> 5;
  const int h  = bswz & 31;
  const int t0 = bswz * 32;           // first token of this image row
  const size_t img = (size_t)bt << 10;

  int srow[3];
  srow[0] = max(h - 1, 0); srow[1] = h; srow[2] = min(h + 1, 31);

  // ---- Phase 1a: K-halo load (48 chunks of 1KB; chunk = slot*16 + tokpair) ----
#pragma unroll
  for (int sweep = 0; sweep < 6; ++sweep) {
    int chunk = sweep * 8 + wid;
    int slot = chunk >> 4, t2 = chunk & 15;
    int tokw = t2 * 2 + (lane >> 5);
    int off  = (lane & 31) * 16;
    size_t grow = img + (size_t)srow[slot] * 32 + tokw;
    const char* ga = (const char*)qkv + grow * 1536 + 512 + off;  // K at elem 256
    __builtin_amdgcn_global_load_lds((gptr_t)ga, (lptr_t)(Halo + chunk * 1024), 16, 0, 0);
  }
  __syncthreads();

  // scores + softmax: 4 tokens per wave; lane: head = lane>>3, d = lane*4
  float wgt[4][9];
#pragma unroll
  for (int i = 0; i < 4; ++i) {
    int tloc = wid * 4 + i;     // == w coordinate
    s16x4 qr = *(const s16x4*)(qkv + (size_t)(t0 + tloc) * 768 + lane * 4);
    f32x4 q;
#pragma unroll
    for (int e = 0; e < 4; ++e) q[e] = bf2f(qr[e]);
    float sc[9];
#pragma unroll
    for (int s = 0; s < 3; ++s) {
#pragma unroll
      for (int dw = -1; dw <= 1; ++dw) {
        const int j = s * 3 + (dw + 1);
        int cw = min(max(tloc + dw, 0), 31);
        s16x4 kr = *(const s16x4*)(Halo + (s * 32 + cw) * 512 + lane * 8);
        float p = 0.f;
#pragma unroll
        for (int e = 0; e < 4; ++e) p += q[e] * bf2f(kr[e]);
        p += __shfl_xor(p, 1);
        p += __shfl_xor(p, 2);
        p += __shfl_xor(p, 4);
        sc[j] = p * 0.17677669529663687f;  // 1/sqrt(32)
      }
    }
    float mx = sc[0];
#pragma unroll
    for (int j = 1; j < 9; ++j) mx = fmaxf(mx, sc[j]);
    float den = 0.f;
#pragma unroll
    for (int j = 0; j < 9; ++j) { sc[j] = __expf(sc[j] - mx); den += sc[j]; }
    float inv = 1.0f / den;
#pragma unroll
    for (int j = 0; j < 9; ++j) wgt[i][j] = sc[j] * inv;
  }
  __syncthreads();  // all K reads done before V overwrites halo

  // ---- Phase 1b: V-halo load ----
#pragma unroll
  for (int sweep = 0; sweep < 6; ++sweep) {
    int chunk = sweep * 8 + wid;
    int slot = chunk >> 4, t2 = chunk & 15;
    int tokw = t2 * 2 + (lane >> 5);
    int off  = (lane & 31) * 16;
    size_t grow = img + (size_t)srow[slot] * 32 + tokw;
    const char* ga = (const char*)qkv + grow * 1536 + 1024 + off;  // V at elem 512
    __builtin_amdgcn_global_load_lds((gptr_t)ga, (lptr_t)(Halo + chunk * 1024), 16, 0, 0);
  }
  __syncthreads();

#pragma unroll
  for (int i = 0; i < 4; ++i) {
    int tloc = wid * 4 + i;
    f32x4 o = {};
#pragma unroll
    for (int s = 0; s < 3; ++s) {
#pragma unroll
      for (int dw = -1; dw <= 1; ++dw) {
        const int j = s * 3 + (dw + 1);
        int cw = min(max(tloc + dw, 0), 31);
        s16x4 vr = *(const s16x4*)(Halo + (s * 32 + cw) * 512 + lane * 8);
        float wj = wgt[i][j];
#pragma unroll
        for (int e = 0; e < 4; ++e) o[e] += wj * bf2f(vr[e]);
      }
    }
    s16x4 ov;
#pragma unroll
    for (int e = 0; e < 4; ++e) ov[e] = (short)f2bf(o[e]);
    int byte = (lane * 8) ^ ((tloc & 7) << 4);
    *(s16x4*)(Asm + tloc * 512 + byte) = ov;
  }

  // ---- Phase 2: out-GEMM. 8 waves = 2(m) x 4(n); wave-tile 16x64 ----
  const int wave_m = wid >> 2;
  const int wave_n = wid & 3;
  f32x4 acc[4] = {};

  for (int ks = 0; ks < 4; ++ks) {
    __syncthreads();  // V/A reads done (ks=0) or prev Bsm reads done
#pragma unroll
    for (int it = 0; it < 4; ++it) {
      int base     = it * 8192 + wid * 1024;
      int lane_lin = base + lane * 16;
      int row  = lane_lin >> 7;   // 128B rows
      int off  = lane_lin & 127;
      int soff = off ^ ((row & 7) << 4);
      const char* gb = (const char*)(wto + (size_t)row * K_DIM + ks * 64) + soff;
      __builtin_amdgcn_global_load_lds((gptr_t)gb, (lptr_t)(Halo + base), 16, 0, 0);
    }
    __syncthreads();

#pragma unroll
    for (int kk = 0; kk < 2; ++kk) {
      s16x8 af, bf[4];
      {
        int r    = wave_m * 16 + (lane & 15);
        int byte = ks * 128 + kk * 64 + ((lane >> 4) * 16);
        af = *(const s16x8*)(Asm + r * 512 + (byte ^ ((r & 7) << 4)));
      }
#pragma unroll
      for (int n = 0; n < 4; ++n) {
        int r    = wave_n * 64 + n * 16 + (lane & 15);
        int byte = kk * 64 + ((lane >> 4) * 16);
        bf[n] = *(const s16x8*)(Halo + r * 128 + (byte ^ ((r & 7) << 4)));
      }
#pragma unroll
      for (int n = 0; n < 4; ++n)
        acc[n] = __builtin_amdgcn_mfma_f32_16x16x32_bf16(af, bf[n], acc[n], 0, 0, 0);
    }
  }

  const int c0 = lane & 15;
  const int r0 = (lane >> 4) * 4;
#pragma unroll
  for (int n = 0; n < 4; ++n) {
    int col = wave_n * 64 + n * 16 + c0;
    float bb = bo[col];
#pragma unroll
    for (int r = 0; r < 4; ++r) {
      int row = t0 + wave_m * 16 + r0 + r;
      out[(size_t)row * D_ + col] = acc[n][r] + bb + x[(size_t)row * D_ + col];
    }
  }
}

extern "C" void kernel_launch(void* const* d_in, const int* in_sizes, int n_in,
                              void* d_out, int out_size, void* d_ws, size_t ws_size,
                              hipStream_t stream) {
  const float* x  = (const float*)d_in[0];
  const float* lg = (const float*)d_in[1];
  const float* lb = (const float*)d_in[2];
  const float* wq = (const float*)d_in[3];
  const float* bq = (const float*)d_in[4];
  const float* wk = (const float*)d_in[5];
  const float* bk = (const float*)d_in[6];
  const float* wv = (const float*)d_in[7];
  const float* bv = (const float*)d_in[8];
  const float* wo = (const float*)d_in[9];
  const float* bo = (const float*)d_in[10];
  float* out = (float*)d_out;

  char* ws = (char*)d_ws;
  unsigned short* xn    = (unsigned short*)ws;                 // 16384*256*2
  unsigned short* qkv   = (unsigned short*)(ws + 8388608);     // 16384*768*2
  unsigned short* wtqkv = (unsigned short*)(ws + 33554432);    // 768*256*2
  unsigned short* wto   = (unsigned short*)(ws + 33947648);    // 256*256*2

  prep_kernel<<<4352, 256, 0, stream>>>(x, lg, lb, xn, wq, wk, wv, wo, wtqkv, wto);
  gemm_qkv_kernel<<<dim3(6, 128), 256, 0, stream>>>(xn, wtqkv, bq, bk, bv, qkv);
  attn_ogemm_kernel<<<512, 512, 0, stream>>>(qkv, wto, bo, x, out);
}